// Round 1
// baseline (276.130 us; speedup 1.0000x reference)
//
#include <hip/hip_runtime.h>
#include <hip/hip_bf16.h>
#include <math.h>

// Problem sizes (fixed by the reference)
#define BQ   8
#define SEQ  2048
#define DV   512
#define DA   512
#define MTOT (BQ * SEQ)   // 16384

typedef __attribute__((ext_vector_type(8))) short bf16x8;
typedef __attribute__((ext_vector_type(4))) float f32x4;
typedef __attribute__((ext_vector_type(4))) short short4v;

__device__ __forceinline__ unsigned short f2bf(float f) {
    union { float f; unsigned u; } c; c.f = f;
    unsigned u = c.u;
    unsigned r = (u + 0x7fffu + ((u >> 16) & 1u)) >> 16;
    return (unsigned short)r;
}
__device__ __forceinline__ float bf2f(unsigned short h) {
    union { unsigned u; float f; } c; c.u = ((unsigned)h) << 16;
    return c.f;
}

__device__ __forceinline__ void gload_lds16(const void* g, void* l) {
    __builtin_amdgcn_global_load_lds(
        (const __attribute__((address_space(1))) void*)g,
        (__attribute__((address_space(3))) void*)l,
        16, 0, 0);
}

// ---------------- convert f32 -> bf16 (vectorized) ----------------
__global__ __launch_bounds__(256) void cvt_f32_bf16(
    const float* __restrict__ in, short* __restrict__ out, int n4)
{
    int i = blockIdx.x * blockDim.x + threadIdx.x;
    int stride = gridDim.x * blockDim.x;
    for (; i < n4; i += stride) {
        float4 v = ((const float4*)in)[i];
        short4v o;
        o[0] = (short)f2bf(v.x);
        o[1] = (short)f2bf(v.y);
        o[2] = (short)f2bf(v.z);
        o[3] = (short)f2bf(v.w);
        ((short4v*)out)[i] = o;
    }
}

// ---------------- GEMM: C[M,N] = A[M,K] * B[N,K]^T  (bf16 in, f32 acc) ----
// OMODE 0: bf16 C, row-major ldc        (optionally batched via strides)
// OMODE 1: f32  C, row-major ldc        (batched)
// OMODE 2: bf16 C transposed per batch: C[b][n][s] with s = row % SEQ
// 128x128 tile, BK=32, 256 threads = 4 waves (2x2), each wave 64x64.
template<int OMODE>
__global__ __launch_bounds__(256, 2) void gemm_bt(
    const short* __restrict__ A, const short* __restrict__ B, void* __restrict__ Cv,
    int M, int N, int K, int lda, int ldb, int ldc,
    long strideA, long strideB, long strideC, float scale)
{
    __shared__ __align__(16) short sA[128 * 32];
    __shared__ __align__(16) short sB[128 * 32];

    const int tid  = threadIdx.x;
    const int wave = tid >> 6;
    const int lane = tid & 63;
    const int wr = wave >> 1, wc = wave & 1;
    const int brow = blockIdx.y * 128;
    const int bcol = blockIdx.x * 128;
    const int z = blockIdx.z;
    A += (size_t)z * strideA;
    B += (size_t)z * strideB;

    const int r16 = lane & 15;
    const int kq  = lane >> 4;

    f32x4 acc[4][4];
    const f32x4 fz = {0.f, 0.f, 0.f, 0.f};
    #pragma unroll
    for (int i = 0; i < 4; ++i)
        #pragma unroll
        for (int j = 0; j < 4; ++j) acc[i][j] = fz;

    for (int k0 = 0; k0 < K; k0 += 32) {
        // ---- stage A,B tiles (128x32 bf16 each) via global_load_lds x16B
        #pragma unroll
        for (int j = 0; j < 2; ++j) {
            int slot = wave * 128 + j * 64 + lane;   // 16B slot index, 0..511
            int row  = slot >> 2;                    // 4 slots per 32-elem row
            int cs   = slot & 3;                     // which 8-elem chunk
            const short* ga = A + (size_t)(brow + row) * lda + k0 + cs * 8;
            const short* gb = B + (size_t)(bcol + row) * ldb + k0 + cs * 8;
            int ldsoff = (wave * 128 + j * 64) * 8;  // shorts (16B per slot)
            gload_lds16(ga, &sA[ldsoff]);
            gload_lds16(gb, &sB[ldsoff]);
        }
        __syncthreads();

        bf16x8 a[4], b[4];
        #pragma unroll
        for (int i = 0; i < 4; ++i)
            a[i] = *(const bf16x8*)&sA[(wr * 64 + i * 16 + r16) * 32 + kq * 8];
        #pragma unroll
        for (int j = 0; j < 4; ++j)
            b[j] = *(const bf16x8*)&sB[(wc * 64 + j * 16 + r16) * 32 + kq * 8];

        #pragma unroll
        for (int i = 0; i < 4; ++i)
            #pragma unroll
            for (int j = 0; j < 4; ++j)
                acc[i][j] = __builtin_amdgcn_mfma_f32_16x16x32_bf16(a[i], b[j], acc[i][j], 0, 0, 0);
        __syncthreads();
    }

    // ---- epilogue: C/D layout col=lane&15, row=(lane>>4)*4+t
    #pragma unroll
    for (int i = 0; i < 4; ++i) {
        int row0 = brow + wr * 64 + i * 16 + (lane >> 4) * 4;
        #pragma unroll
        for (int j = 0; j < 4; ++j) {
            int col = bcol + wc * 64 + j * 16 + (lane & 15);
            f32x4 v = acc[i][j];
            #pragma unroll
            for (int t = 0; t < 4; ++t) {
                float val = v[t] * scale;
                int row = row0 + t;
                if (OMODE == 0) {
                    ((short*)Cv)[(size_t)z * strideC + (size_t)row * ldc + col] = (short)f2bf(val);
                } else if (OMODE == 1) {
                    ((float*)Cv)[(size_t)z * strideC + (size_t)row * ldc + col] = val;
                } else {
                    int bb = row >> 11;            // row / SEQ
                    int s  = row & (SEQ - 1);      // row % SEQ
                    ((short*)Cv)[(size_t)bb * ((size_t)N * SEQ) + (size_t)col * SEQ + s] = (short)f2bf(val);
                }
            }
        }
    }
}

// ---------------- row softmax over 2048 bf16, in place, 1 wave / row ------
__global__ __launch_bounds__(256) void softmax_rows(short* __restrict__ S)
{
    int row  = blockIdx.x * 4 + (threadIdx.x >> 6);
    int lane = threadIdx.x & 63;
    size_t base = (size_t)row * SEQ;

    float v[32];
    #pragma unroll
    for (int c = 0; c < 4; ++c) {
        bf16x8 x = *(const bf16x8*)&S[base + c * 512 + lane * 8];
        #pragma unroll
        for (int e = 0; e < 8; ++e) v[c * 8 + e] = bf2f((unsigned short)x[e]);
    }
    float mx = -1e30f;
    #pragma unroll
    for (int i = 0; i < 32; ++i) mx = fmaxf(mx, v[i]);
    #pragma unroll
    for (int off = 32; off > 0; off >>= 1) mx = fmaxf(mx, __shfl_xor(mx, off));

    float sum = 0.f;
    #pragma unroll
    for (int i = 0; i < 32; ++i) { v[i] = __expf(v[i] - mx); sum += v[i]; }
    #pragma unroll
    for (int off = 32; off > 0; off >>= 1) sum += __shfl_xor(sum, off);
    float inv = 1.0f / sum;

    #pragma unroll
    for (int c = 0; c < 4; ++c) {
        bf16x8 x;
        #pragma unroll
        for (int e = 0; e < 8; ++e) x[e] = (short)f2bf(v[c * 8 + e] * inv);
        *(bf16x8*)&S[base + c * 512 + lane * 8] = x;
    }
}

extern "C" void kernel_launch(void* const* d_in, const int* in_sizes, int n_in,
                              void* d_out, int out_size, void* d_ws, size_t ws_size,
                              hipStream_t stream)
{
    const float* x  = (const float*)d_in[0];
    const float* Wq = (const float*)d_in[1];
    const float* Wk = (const float*)d_in[2];
    const float* Wv = (const float*)d_in[3];
    float* out = (float*)d_out;

    // workspace layout (bf16 shorts)
    short* xb  = (short*)d_ws;                     // 16384*512
    short* wqb = xb  + (size_t)MTOT * DV;
    short* wkb = wqb + (size_t)DA * DV;
    short* wvb = wkb + (size_t)DA * DV;
    short* Qb  = wvb + (size_t)DV * DV;            // 16384*512
    short* Kb  = Qb  + (size_t)MTOT * DA;
    short* VT  = Kb  + (size_t)MTOT * DA;          // [B][512][2048]
    short* Sc  = VT  + (size_t)MTOT * DV;          // 8*2048*2048

    const float qscale = 0.04419417382415922f;     // 1/sqrt(512)

    // 1) convert inputs to bf16
    cvt_f32_bf16<<<8192, 256, 0, stream>>>(x,  xb,  (MTOT * DV) / 4);
    cvt_f32_bf16<<<256,  256, 0, stream>>>(Wq, wqb, (DA * DV) / 4);
    cvt_f32_bf16<<<256,  256, 0, stream>>>(Wk, wkb, (DA * DV) / 4);
    cvt_f32_bf16<<<256,  256, 0, stream>>>(Wv, wvb, (DV * DV) / 4);

    dim3 blk(256);

    // 2) projections: M=16384, N=512, K=512  (grid: N/128 x M/128)
    gemm_bt<0><<<dim3(4, 128, 1), blk, 0, stream>>>(
        xb, wqb, Qb, MTOT, DA, DV, DV, DV, DA, 0, 0, 0, qscale);
    gemm_bt<0><<<dim3(4, 128, 1), blk, 0, stream>>>(
        xb, wkb, Kb, MTOT, DA, DV, DV, DV, DA, 0, 0, 0, 1.0f);
    gemm_bt<2><<<dim3(4, 128, 1), blk, 0, stream>>>(
        xb, wvb, VT, MTOT, DV, DV, DV, DV, SEQ, 0, 0, 0, 1.0f);

    // 3) scores: per batch  2048x2048x512, bf16 out (Q already scaled)
    gemm_bt<0><<<dim3(16, 16, BQ), blk, 0, stream>>>(
        Qb, Kb, Sc, SEQ, SEQ, DA, DA, DA, SEQ,
        (long)SEQ * DA, (long)SEQ * DA, (long)SEQ * SEQ, 1.0f);

    // 4) softmax rows (in place on Sc)
    softmax_rows<<<(BQ * SEQ) / 4, 256, 0, stream>>>(Sc);

    // 5) PV: per batch 2048x512x2048, f32 out -> d_out
    gemm_bt<1><<<dim3(4, 16, BQ), blk, 0, stream>>>(
        Sc, VT, out, SEQ, DV, SEQ, SEQ, SEQ, DV,
        (long)SEQ * SEQ, (long)DV * SEQ, (long)SEQ * DV, 1.0f);
}